// Round 13
// baseline (187.492 us; speedup 1.0000x reference)
//
#include <hip/hip_runtime.h>
#include <math.h>

#define BB   4
#define HH   96
#define WW   96
#define HW   (HH * WW)          // 9216
#define CIN  64
#define COUT 64
#define NPL  17                 // activation planes: fi 0-7, fj(phys) 8-15, flow 16
#define HWP  (HW + 1)           // uint4 per plane: HW positions + zero slot at HW
#define NROW (BB * HW)          // 36864
#define NSTRIP (NROW / 16)      // 2304 strips of 16 positions
#define BPX3 (NSTRIP / 8)       // 288 strips per XCD slice
#define GRIDN 384               // mono blocks; 6 strips each (2304 = 384*6);
                                // HW capacity at (512,4) is 512 blocks -> safe
#define NA   (9 * 5 * 2 * 512)  // wa2f elements (46080), fragment-dense
#define NW   (9 * 2 * 4 * 512)  // wb2f elements (36864), fragment-dense
#define PXB2 (NROW / 32)        // 1152 prep X-jobs (64 rows, half channels)
#define PWBLK 324               // weight jobs covering NA+NW elements
#define TSX  35                 // prep LDS tile stride (dwords), conflict-free
#define NIT  (NPL * 54)         // 918 staging items (17 planes x 54 positions)
#define CNT_OFF ((size_t)BB * NPL * HWP * 16 + (size_t)NA * 2 + (size_t)NW * 2)

typedef short v8s __attribute__((ext_vector_type(8)));   // 8 bf16 = 4 VGPRs
typedef float v4f __attribute__((ext_vector_type(4)));

__device__ __forceinline__ unsigned short f2bf(float f) {
    unsigned u = __float_as_uint(f);
    return (unsigned short)((u + 0x7FFFu + ((u >> 16) & 1u)) >> 16);  // RTN-even
}
__device__ __forceinline__ unsigned pack2(float a, float b) {
    return (unsigned)f2bf(a) | ((unsigned)f2bf(b) << 16);
}
__device__ __forceinline__ unsigned bil2(unsigned a, unsigned b, unsigned c,
                                         unsigned d, float w00, float w01,
                                         float w10, float w11) {
    float lo = w00 * __uint_as_float(a << 16) + w01 * __uint_as_float(b << 16)
             + w10 * __uint_as_float(c << 16) + w11 * __uint_as_float(d << 16);
    float hi = w00 * __uint_as_float(a & 0xffff0000u)
             + w01 * __uint_as_float(b & 0xffff0000u)
             + w10 * __uint_as_float(c & 0xffff0000u)
             + w11 * __uint_as_float(d & 0xffff0000u);
    return pack2(lo, hi);
}

// ---------------------------------------------------------------------------
// R27: ONE plain-launch kernel. Prep (R10's known-good jobs, 2 rounds of
// 256-thread job-pairs) -> atomic device barrier (graph-capture-safe; R8's
// cooperative launch was not) -> fused phase (R10 body, 6 strips/block).
// Co-residency: (512,4) bound -> VGPR<=128, LDS 34.6KB -> capacity 2/CU =
// 512 blocks >= GRIDN=384 with margin; spin cannot deadlock.
// Counter in workspace past our data, zeroed by 4-B hipMemsetAsync.
// ---------------------------------------------------------------------------
__global__ __launch_bounds__(512, 4) void mono_kernel(
    const float* __restrict__ fi, const float* __restrict__ fj,
    const float* __restrict__ fl, const float* __restrict__ w_off,
    const float* __restrict__ w_mod, const float* __restrict__ w_reg,
    const float* __restrict__ b_off, const float* __restrict__ b_mod,
    uint4* __restrict__ xp, unsigned short* __restrict__ wa2f,
    unsigned short* __restrict__ wb2f, unsigned* __restrict__ cnt,
    float* __restrict__ out)
{
    // LDS: pool 16KB (prep tileA 9K / patchL 14.7K / red2 16K),
    //      red1 16KB (prep tileB 9K / ph1 partials), lraw 1.8KB = 34.6KB
    __shared__ __align__(16) unsigned char pool[16384];
    __shared__ __align__(16) float red1[8][8][64];
    __shared__ float lraw[16 * 28];

    int tid  = threadIdx.x;
    int half = tid >> 8;                    // 256-thread sub-block
    int stid = tid & 255;

    // ==================== PREP PHASE: 2 rounds of job-pairs ====================
#pragma unroll 1
    for (int it = 0; it < 2; ++it) {
        int job = it * (GRIDN * 2) + (int)blockIdx.x * 2 + half;  // 0..1535
        unsigned* tile = half ? (unsigned*)red1 : (unsigned*)pool;
        int p = stid & 63, cgp = stid >> 6;
        bool isX = job < PXB2;
        int u = job >> 1;                   // X-job strip id (xh == half)
        int r0 = u * 64;
        int b = r0 / HW;
        int hwb = r0 - b * HW;
        int hw = hwb + p;
        uint4* xpb = xp + (size_t)b * NPL * HWP;

        if (isX && half == 0) {             // fi pack
            const float* pi = fi + (size_t)b * CIN * HW + hw;
#pragma unroll
            for (int d = 0; d < 8; ++d) {
                int c = cgp * 16 + 2 * d;
                tile[p * TSX + cgp * 8 + d] =
                    pack2(pi[(size_t)c * HW], pi[(size_t)(c + 1) * HW]);
            }
        } else if (isX) {                   // fj pack + flow
            const float* pj = fj + (size_t)b * CIN * HW + hw;
#pragma unroll
            for (int d = 0; d < 8; ++d) {
                int c = cgp * 16 + 2 * d;
                tile[p * TSX + cgp * 8 + d] =
                    pack2(pj[(size_t)c * HW], pj[(size_t)(c + 1) * HW]);
            }
            if (cgp == 0) {
                const float* pf = fl + (size_t)b * 2 * HW + hw;
                tile[p * TSX + 32] = pack2(pf[0], pf[HW]);
            }
        } else if (job < PXB2 + PWBLK) {    // weight job (no LDS)
            int e = (job - PXB2) * 256 + stid;
            if (e < NA) {                   // wa2f, fragment-dense
                int t  = e / 5120;
                int r1 = e - t * 5120;
                int ks = r1 >> 10;
                int r2 = r1 & 1023;
                int nt = r2 >> 9;
                int l9 = r2 & 511;
                int l  = l9 >> 3, ee = l9 & 7;
                int m  = l & 15, g = l >> 4;
                int oc = nt * 16 + m;
                int ch = ks * 32 + g * 8 + ee;
                float v = 0.0f;
                if (oc < 27 && ch < 130) {
                    if (oc < 18) v = w_off[((size_t)oc * 130 + ch) * 9 + t];
                    else         v = w_mod[((size_t)(oc - 18) * 130 + ch) * 9 + t];
                }
                wa2f[e] = f2bf(v);
            } else {
                int e2 = e - NA;
                if (e2 < NW) {              // wb2f, fragment-dense
                    int k  = e2 >> 12;
                    int r1 = e2 & 4095;
                    int ks = r1 >> 11;
                    int r2 = r1 & 2047;
                    int nt = r2 >> 9;
                    int l9 = r2 & 511;
                    int l  = l9 >> 3, ee = l9 & 7;
                    int m  = l & 15, g = l >> 4;
                    int o  = nt * 16 + m;
                    int c  = ks * 32 + g * 8 + ee;
                    wb2f[e2] = f2bf(w_reg[((size_t)o * 64 + c) * 9 + k]);
                }
            }
        } else if (job == PXB2 + PWBLK) {   // zero slots
            if (stid < BB * NPL) {
                int bz = stid / NPL, pl = stid - bz * NPL;
                uint4 z = {0u, 0u, 0u, 0u};
                xp[((size_t)bz * NPL + pl) * HWP + HW] = z;
            }
        }
        __syncthreads();                    // uniform sync 1 (pack done)
        if (isX && half == 0) {             // fi plane stores
#pragma unroll
            for (int i = 0; i < 2; ++i) {
                int it2 = i * 256 + stid;
                int pl = it2 >> 6, rl = it2 & 63;
                const unsigned* s = &tile[rl * TSX + pl * 4];
                uint4 v = {s[0], s[1], s[2], s[3]};
                xpb[(size_t)pl * HWP + hwb + rl] = v;
            }
        } else if (isX) {                   // fj plane stores (permuted) + flow
#pragma unroll
            for (int i = 0; i < 2; ++i) {
                int it2 = i * 256 + stid;
                int pl = it2 >> 6, rl = it2 & 63;
                int o  = (pl >> 1) + (pl & 1) * 4;
                const unsigned* s = &tile[rl * TSX + o * 4];
                uint4 v = {s[0], s[1], s[2], s[3]};
                xpb[(size_t)(8 + pl) * HWP + hwb + rl] = v;
            }
            if (stid < 64) {
                uint4 v = {tile[stid * TSX + 32], 0u, 0u, 0u};
                xpb[(size_t)16 * HWP + hwb + stid] = v;
            }
        }
        __syncthreads();                    // uniform sync 2 (tile reusable)
    }

    // ==================== DEVICE BARRIER (atomic, capture-safe) ====================
    if (tid == 0) {
        __threadfence();                    // prep writes -> device scope
        __hip_atomic_fetch_add(cnt, 1u, __ATOMIC_ACQ_REL,
                               __HIP_MEMORY_SCOPE_AGENT);
        while (__hip_atomic_load(cnt, __ATOMIC_ACQUIRE,
                                 __HIP_MEMORY_SCOPE_AGENT) < (unsigned)GRIDN)
            __builtin_amdgcn_s_sleep(2);
    }
    __syncthreads();                        // block observes barrier passed

    // ==================== FUSED PHASE: 6 strips per block ====================
    uint4* patchL = (uint4*)pool;
    float* red2   = (float*)pool;           // [4][16][64]

    int l = tid & 63;
    int wid = __builtin_amdgcn_readfirstlane(tid >> 6);  // 0..7
    int m = l & 15, g = l >> 4;

#pragma unroll 1
    for (int sj = (int)blockIdx.x; sj < NSTRIP; sj += GRIDN) {
        int strip = (sj & 7) * BPX3 + (sj >> 3);    // XCD-contiguous
        int b = strip / (HW / 16);          // wave-uniform
        int hw0 = (strip - b * (HW / 16)) * 16;
        int hw = hw0 + m;
        int x = hw % WW, y = hw / WW;
        int y0b = hw0 / WW, x0b = hw0 - y0b * WW;

        const uint4* xpb = xp + (size_t)b * NPL * HWP;

        // ---- Stage 918 items: plane-major, contiguous 288-B runs ----
#pragma unroll
        for (int i = 0; i < 2; ++i) {
            int item = i * 512 + tid;
            if (item < NIT) {
                int pl  = item / 54;
                int rm  = item - pl * 54;
                int run = rm / 18;
                int r18 = rm - run * 18;
                int yy = y0b + run - 1;
                int xx = x0b - 1 + r18;
                bool ok = ((unsigned)yy < HH) && ((unsigned)xx < WW);
                int pos = ok ? (yy * WW + xx) : HW;     // HW = zero slot
                patchL[item] = xpb[(size_t)pl * HWP + pos];
            }
        }
        __syncthreads();                    // barrier S

        // ---- Phase 1: conv partials, 45 units over 8 waves ----
        v4f acc0 = {0.f, 0.f, 0.f, 0.f};
        v4f acc1 = {0.f, 0.f, 0.f, 0.f};
        {
            int nu = (wid < 5) ? 6 : 5;     // wave-uniform unit count
#pragma unroll
            for (int i = 0; i < 6; ++i) {
                if (i < nu) {
                    int u = wid + 8 * i;    // unit = t*5+ks, uniform
                    int t = u / 5, ks = u - 5 * t;
                    int r = (t / 3) * 18 + (t % 3) + m;
                    v8s a;
                    if (ks == 4) {          // flow plane; zero for g>0
                        uint4 t4 = patchL[16 * 54 + r];
                        if (g) t4 = (uint4){0u, 0u, 0u, 0u};
                        a = __builtin_bit_cast(v8s, t4);
                    } else {
                        int pl = (ks == 0) ? g : (ks == 1) ? 4 + g
                               : (ks == 2) ? 8 + 2 * g : 9 + 2 * g;
                        a = *(const v8s*)&patchL[pl * 54 + r];
                    }
                    const unsigned short* wp =
                        wa2f + ((size_t)(u * 2)) * 512 + l * 8;
                    v8s b0 = *(const v8s*)(wp);
                    v8s b1 = *(const v8s*)(wp + 512);
                    acc0 = __builtin_amdgcn_mfma_f32_16x16x32_bf16(a, b0, acc0, 0, 0, 0);
                    acc1 = __builtin_amdgcn_mfma_f32_16x16x32_bf16(a, b1, acc1, 0, 0, 0);
                }
            }
        }

        {                                   // publish 8 dwords/lane
#pragma unroll
            for (int j = 0; j < 4; ++j) red1[wid][j][l] = acc0[j];
#pragma unroll
            for (int j = 0; j < 4; ++j) red1[wid][4 + j][l] = acc1[j];
        }
        __syncthreads();                    // barrier A (patchL dead)

        {   // reduce + epilogue: wave w owns output-dword slot j = w
            int j = wid;
            float v = 0.f;
#pragma unroll
            for (int sw = 0; sw < 8; ++sw) v += red1[sw][j][l];
            int r = j & 3;
            int oc = (j < 4) ? m : 16 + m;
            int pos = g * 4 + r;
            if (oc < 18) {
                lraw[pos * 28 + oc] = v + b_off[oc];
            } else if (oc < 27) {
                lraw[pos * 28 + oc] =
                    2.0f / (1.0f + __expf(-(v + b_mod[oc - 18])));
            }
        }
        __syncthreads();                    // barrier B (red1 dead, red2 born)

        // ---- Phase 2: wave w owns tap w; tap 8 split by ks to waves 6/7 ----
        v4f acc[4];
#pragma unroll
        for (int nt = 0; nt < 4; ++nt) acc[nt] = (v4f){0.f, 0.f, 0.f, 0.f};

        auto do_tap = [&](int k) {
            int ky = k / 3, kx = k - 3 * ky;
            float dy = lraw[m * 28 + 2 * k];
            float dx = lraw[m * 28 + 2 * k + 1];
            float mm = lraw[m * 28 + 18 + k];

            float py = (float)(y - 1 + ky) + dy;
            float px = (float)(x - 1 + kx) + dx;
            float fy = floorf(py), fx = floorf(px);
            int   y0 = (int)fy,    x0 = (int)fx;
            float wy = py - fy,    wx = px - fx;
            int   y1 = y0 + 1,     x1 = x0 + 1;

            bool y0v = (y0 >= 0) && (y0 < HH);
            bool y1v = (y1 >= 0) && (y1 < HH);
            bool x0v = (x0 >= 0) && (x0 < WW);
            bool x1v = (x1 >= 0) && (x1 < WW);

            float w00 = (1.f - wy) * (1.f - wx) * ((y0v && x0v) ? mm : 0.f);
            float w01 = (1.f - wy) * wx         * ((y0v && x1v) ? mm : 0.f);
            float w10 = wy * (1.f - wx)         * ((y1v && x0v) ? mm : 0.f);
            float w11 = wy * wx                 * ((y1v && x1v) ? mm : 0.f);

            int y0c = min(max(y0, 0), HH - 1), y1c = min(max(y1, 0), HH - 1);
            int x0c = min(max(x0, 0), WW - 1), x1c = min(max(x1, 0), WW - 1);
            int i00 = y0c * WW + x0c, i01 = y0c * WW + x1c;
            int i10 = y1c * WW + x0c, i11 = y1c * WW + x1c;

            const uint4* p0 = xpb + (size_t)(8 + 2 * g) * HWP;
            const uint4* p1 = p0 + HWP;

            uint4 a00 = p0[i00];
            uint4 a01 = p0[i01];
            uint4 a10 = p0[i10];
            uint4 a11 = p0[i11];
            uint4 c00 = p1[i00];
            uint4 c01 = p1[i01];
            uint4 c10 = p1[i10];
            uint4 c11 = p1[i11];

            uint4 ov0, ov1;
            ov0.x = bil2(a00.x, a01.x, a10.x, a11.x, w00, w01, w10, w11);
            ov0.y = bil2(a00.y, a01.y, a10.y, a11.y, w00, w01, w10, w11);
            ov0.z = bil2(a00.z, a01.z, a10.z, a11.z, w00, w01, w10, w11);
            ov0.w = bil2(a00.w, a01.w, a10.w, a11.w, w00, w01, w10, w11);
            ov1.x = bil2(c00.x, c01.x, c10.x, c11.x, w00, w01, w10, w11);
            ov1.y = bil2(c00.y, c01.y, c10.y, c11.y, w00, w01, w10, w11);
            ov1.z = bil2(c00.z, c01.z, c10.z, c11.z, w00, w01, w10, w11);
            ov1.w = bil2(c00.w, c01.w, c10.w, c11.w, w00, w01, w10, w11);
            v8s af0 = __builtin_bit_cast(v8s, ov0);
            v8s af1 = __builtin_bit_cast(v8s, ov1);

#pragma unroll
            for (int nt = 0; nt < 4; ++nt) {
                const unsigned short* wp0 =
                    wb2f + ((size_t)((k * 2 + 0) * 4 + nt)) * 512 + l * 8;
                const unsigned short* wp1 =
                    wb2f + ((size_t)((k * 2 + 1) * 4 + nt)) * 512 + l * 8;
                v8s bb0 = *(const v8s*)wp0;
                v8s bb1 = *(const v8s*)wp1;
                acc[nt] = __builtin_amdgcn_mfma_f32_16x16x32_bf16(af0, bb0, acc[nt], 0, 0, 0);
                acc[nt] = __builtin_amdgcn_mfma_f32_16x16x32_bf16(af1, bb1, acc[nt], 0, 0, 0);
            }
        };

        auto do_half = [&](int k, int ks) {
            int ky = k / 3, kx = k - 3 * ky;
            float dy = lraw[m * 28 + 2 * k];
            float dx = lraw[m * 28 + 2 * k + 1];
            float mm = lraw[m * 28 + 18 + k];

            float py = (float)(y - 1 + ky) + dy;
            float px = (float)(x - 1 + kx) + dx;
            float fy = floorf(py), fx = floorf(px);
            int   y0 = (int)fy,    x0 = (int)fx;
            float wy = py - fy,    wx = px - fx;
            int   y1 = y0 + 1,     x1 = x0 + 1;

            bool y0v = (y0 >= 0) && (y0 < HH);
            bool y1v = (y1 >= 0) && (y1 < HH);
            bool x0v = (x0 >= 0) && (x0 < WW);
            bool x1v = (x1 >= 0) && (x1 < WW);

            float w00 = (1.f - wy) * (1.f - wx) * ((y0v && x0v) ? mm : 0.f);
            float w01 = (1.f - wy) * wx         * ((y0v && x1v) ? mm : 0.f);
            float w10 = wy * (1.f - wx)         * ((y1v && x0v) ? mm : 0.f);
            float w11 = wy * wx                 * ((y1v && x1v) ? mm : 0.f);

            int y0c = min(max(y0, 0), HH - 1), y1c = min(max(y1, 0), HH - 1);
            int x0c = min(max(x0, 0), WW - 1), x1c = min(max(x1, 0), WW - 1);
            int i00 = y0c * WW + x0c, i01 = y0c * WW + x1c;
            int i10 = y1c * WW + x0c, i11 = y1c * WW + x1c;

            const uint4* pk = xpb + (size_t)(8 + 2 * g + ks) * HWP;
            uint4 a00 = pk[i00];
            uint4 a01 = pk[i01];
            uint4 a10 = pk[i10];
            uint4 a11 = pk[i11];

            uint4 ov;
            ov.x = bil2(a00.x, a01.x, a10.x, a11.x, w00, w01, w10, w11);
            ov.y = bil2(a00.y, a01.y, a10.y, a11.y, w00, w01, w10, w11);
            ov.z = bil2(a00.z, a01.z, a10.z, a11.z, w00, w01, w10, w11);
            ov.w = bil2(a00.w, a01.w, a10.w, a11.w, w00, w01, w10, w11);
            v8s af = __builtin_bit_cast(v8s, ov);

#pragma unroll
            for (int nt = 0; nt < 4; ++nt) {
                const unsigned short* wp =
                    wb2f + ((size_t)((k * 2 + ks) * 4 + nt)) * 512 + l * 8;
                v8s bb = *(const v8s*)wp;
                acc[nt] = __builtin_amdgcn_mfma_f32_16x16x32_bf16(af, bb, acc[nt], 0, 0, 0);
            }
        };

        do_tap(wid);
        if (wid == 6) do_half(8, 0);
        if (wid == 7) do_half(8, 1);

        // ---- Two-stage cross-wave reduction (red2 = 4 buffers, 16 KB) ----
        if (wid >= 4) {                     // stage A: waves 4-7 publish
            float* rb = red2 + ((size_t)(wid - 4) * 16) * 64;
#pragma unroll
            for (int nt = 0; nt < 4; ++nt)
#pragma unroll
                for (int r = 0; r < 4; ++r)
                    rb[(nt * 4 + r) * 64 + l] = acc[nt][r];
        }
        __syncthreads();                    // barrier C1
        if (wid < 4) {                      // stage B: waves 0-3 add in place
            float* rb = red2 + ((size_t)wid * 16) * 64;
#pragma unroll
            for (int nt = 0; nt < 4; ++nt)
#pragma unroll
                for (int r = 0; r < 4; ++r) {
                    float t = rb[(nt * 4 + r) * 64 + l] + acc[nt][r];
                    rb[(nt * 4 + r) * 64 + l] = t;
                }
        }
        __syncthreads();                    // barrier C2
        {   // stage C: wave w reduces slots {nt*4+r0, +1} over 4 buffers
            int nt = wid >> 1, r0 = (wid & 1) * 2;
            float v0 = 0.f, v1 = 0.f;
#pragma unroll
            for (int bu = 0; bu < 4; ++bu) {
                v0 += red2[((size_t)bu * 16 + nt * 4 + r0) * 64 + l];
                v1 += red2[((size_t)bu * 16 + nt * 4 + r0 + 1) * 64 + l];
            }
            float* op = out + ((size_t)(b * COUT + nt * 16 + m)) * HW
                      + hw0 + g * 4 + r0;
            float2 s2 = {v0, v1};
            *(float2*)op = s2;
        }
        __syncthreads();                    // barrier E: protect pool reuse
    }
}

extern "C" void kernel_launch(void* const* d_in, const int* in_sizes, int n_in,
                              void* d_out, int out_size, void* d_ws, size_t ws_size,
                              hipStream_t stream)
{
    const float* frame_i = (const float*)d_in[0];
    const float* frame_j = (const float*)d_in[1];
    const float* flow_ij = (const float*)d_in[2];
    const float* w_off   = (const float*)d_in[3];
    const float* b_off   = (const float*)d_in[4];
    const float* w_mod   = (const float*)d_in[5];
    const float* b_mod   = (const float*)d_in[6];
    const float* w_reg   = (const float*)d_in[7];
    float* out = (float*)d_out;

    // workspace: xp uint4[BB*NPL*HWP] (~10 MB) | Wa2f | Wb2f | counter
    uint4* xp = (uint4*)d_ws;
    unsigned short* wa2f = (unsigned short*)(xp + (size_t)BB * NPL * HWP);
    unsigned short* wb2f = wa2f + NA;
    unsigned* cnt = (unsigned*)((char*)d_ws + CNT_OFF);

    hipMemsetAsync(cnt, 0, 4, stream);      // poison-proof barrier init

    mono_kernel<<<GRIDN, 512, 0, stream>>>(
        frame_i, frame_j, flow_ij, w_off, w_mod, w_reg, b_off, b_mod,
        xp, wa2f, wb2f, cnt, out);
}

// Round 14
// 111.990 us; speedup vs baseline: 1.6742x; 1.6742x over previous
//
#include <hip/hip_runtime.h>
#include <math.h>

#define BB   4
#define HH   96
#define WW   96
#define HW   (HH * WW)          // 9216
#define CIN  64
#define COUT 64
#define NPL  17                 // activation planes: fi 0-7, fj(phys) 8-15, flow 16
#define HWP  (HW + 1)           // uint4 per plane: HW positions + zero slot at HW
#define NROW (BB * HW)          // 36864
#define NSTRIP (NROW / 16)      // 2304 strips of 16 positions
#define BPX3 (NSTRIP / 8)       // 288 strips per XCD slice
#define NA   (9 * 5 * 2 * 512)  // wa2f elements (46080), fragment-dense
#define NW   (9 * 2 * 4 * 512)  // wb2f elements (36864), fragment-dense
#define PXB2 (NROW / 32)        // 1152 prep X-blocks (64 rows, half channels)
#define PWBLK 324               // weight blocks covering NA+NW elements
#define TSX  35                 // prep LDS tile stride (dwords), conflict-free
#define NIT  (NPL * 54)         // 918 staging items (17 planes x 54 positions)

typedef short v8s __attribute__((ext_vector_type(8)));   // 8 bf16 = 4 VGPRs
typedef float v4f __attribute__((ext_vector_type(4)));

__device__ __forceinline__ unsigned short f2bf(float f) {
    unsigned u = __float_as_uint(f);
    return (unsigned short)((u + 0x7FFFu + ((u >> 16) & 1u)) >> 16);  // RTN-even
}
__device__ __forceinline__ unsigned pack2(float a, float b) {
    return (unsigned)f2bf(a) | ((unsigned)f2bf(b) << 16);
}
__device__ __forceinline__ unsigned bil2(unsigned a, unsigned b, unsigned c,
                                         unsigned d, float w00, float w01,
                                         float w10, float w11) {
    float lo = w00 * __uint_as_float(a << 16) + w01 * __uint_as_float(b << 16)
             + w10 * __uint_as_float(c << 16) + w11 * __uint_as_float(d << 16);
    float hi = w00 * __uint_as_float(a & 0xffff0000u)
             + w01 * __uint_as_float(b & 0xffff0000u)
             + w10 * __uint_as_float(c & 0xffff0000u)
             + w11 * __uint_as_float(d & 0xffff0000u);
    return pack2(lo, hi);
}

// ---------------------------------------------------------------------------
// Prep (R10, known-good). Plane-major xp[b][pl][HWP]: fi planes 0-7, fj PHYS
// planes 8-15 (pl holds orig chunk (pl>>1)+(pl&1)*4), flow plane 16; index HW
// of each plane is a zero slot.
// ---------------------------------------------------------------------------
__global__ __launch_bounds__(256) void prep_kernel(
    const float* __restrict__ fi, const float* __restrict__ fj,
    const float* __restrict__ fl, const float* __restrict__ w_off,
    const float* __restrict__ w_mod, const float* __restrict__ w_reg,
    uint4* __restrict__ xp, unsigned short* __restrict__ wa2f,
    unsigned short* __restrict__ wb2f)
{
    int blk = blockIdx.x;
    if (blk < PXB2) {
        __shared__ __align__(16) unsigned tile[64 * TSX];  // 9 KB
        int tid = threadIdx.x;
        int p = tid & 63, cg = tid >> 6;    // position, channel-group 0..3
        int u = blk >> 1, half = blk & 1;
        int r0 = u * 64;
        int b = r0 / HW;                    // 64-row strip never straddles b
        int hwb = r0 - b * HW;              // strip base within image
        int hw = hwb + p;
        uint4* xpb = xp + (size_t)b * NPL * HWP;
        if (half == 0) {                    // fi -> planes 0..7
            const float* pi = fi + (size_t)b * CIN * HW + hw;
#pragma unroll
            for (int d = 0; d < 8; ++d) {
                int c = cg * 16 + 2 * d;
                tile[p * TSX + cg * 8 + d] =
                    pack2(pi[(size_t)c * HW], pi[(size_t)(c + 1) * HW]);
            }
            __syncthreads();
#pragma unroll
            for (int i = 0; i < 2; ++i) {   // 512 plane-stores, coalesced
                int it = i * 256 + tid;
                int pl = it >> 6, rl = it & 63;
                const unsigned* s = &tile[rl * TSX + pl * 4];
                uint4 v = {s[0], s[1], s[2], s[3]};
                xpb[(size_t)pl * HWP + hwb + rl] = v;
            }
        } else {                            // fj(phys planes) + flow -> 8..16
            const float* pj = fj + (size_t)b * CIN * HW + hw;
#pragma unroll
            for (int d = 0; d < 8; ++d) {
                int c = cg * 16 + 2 * d;
                tile[p * TSX + cg * 8 + d] =
                    pack2(pj[(size_t)c * HW], pj[(size_t)(c + 1) * HW]);
            }
            if (cg == 0) {
                const float* pf = fl + (size_t)b * 2 * HW + hw;
                tile[p * TSX + 32] = pack2(pf[0], pf[HW]);
            }
            __syncthreads();
#pragma unroll
            for (int i = 0; i < 2; ++i) {   // 512 fj plane-stores (permuted)
                int it = i * 256 + tid;
                int pl = it >> 6, rl = it & 63;        // phys plane 0..7
                int o  = (pl >> 1) + (pl & 1) * 4;     // orig chunk
                const unsigned* s = &tile[rl * TSX + o * 4];
                uint4 v = {s[0], s[1], s[2], s[3]};
                xpb[(size_t)(8 + pl) * HWP + hwb + rl] = v;
            }
            if (tid < 64) {                 // flow plane 16
                uint4 v = {tile[tid * TSX + 32], 0u, 0u, 0u};
                xpb[(size_t)16 * HWP + hwb + tid] = v;
            }
        }
    } else if (blk < PXB2 + PWBLK) {
        int e = (blk - PXB2) * 256 + threadIdx.x;
        if (e < NA) {                       // wa2f, fragment-dense
            int t  = e / 5120;
            int r1 = e - t * 5120;
            int ks = r1 >> 10;
            int r2 = r1 & 1023;
            int nt = r2 >> 9;
            int l9 = r2 & 511;
            int l  = l9 >> 3, ee = l9 & 7;
            int m  = l & 15, g = l >> 4;
            int oc = nt * 16 + m;
            int ch = ks * 32 + g * 8 + ee;
            float v = 0.0f;
            if (oc < 27 && ch < 130) {
                if (oc < 18) v = w_off[((size_t)oc * 130 + ch) * 9 + t];
                else         v = w_mod[((size_t)(oc - 18) * 130 + ch) * 9 + t];
            }
            wa2f[e] = f2bf(v);
        } else {
            int e2 = e - NA;
            if (e2 < NW) {                  // wb2f, fragment-dense
                int k  = e2 >> 12;
                int r1 = e2 & 4095;
                int ks = r1 >> 11;
                int r2 = r1 & 2047;
                int nt = r2 >> 9;
                int l9 = r2 & 511;
                int l  = l9 >> 3, ee = l9 & 7;
                int m  = l & 15, g = l >> 4;
                int o  = nt * 16 + m;
                int c  = ks * 32 + g * 8 + ee;
                wb2f[e2] = f2bf(w_reg[((size_t)o * 64 + c) * 9 + k]);
            }
        }
    } else {
        if (threadIdx.x < BB * NPL) {       // 68 zero slots (index HW per plane)
            int bz = threadIdx.x / NPL, pl = threadIdx.x - bz * NPL;
            uint4 z = {0u, 0u, 0u, 0u};
            xp[((size_t)bz * NPL + pl) * HWP + HW] = z;
        }
    }
}

// ---------------------------------------------------------------------------
// Fused conv + deform. R28 = R10 body with ONE change: ph2 reduction is back
// to single-stage over 8 buffers — buffers 0-3 live in pool (patchL's 16 KB,
// dead after barrier A) and buffers 4-7 live in red1 (dead after barrier B).
// Removes barrier C2 and the stage-B LDS read-modify-write pass from the
// per-block critical path. Barriers: S, A, B, C (was S, A, B, C1, C2).
// ---------------------------------------------------------------------------
__global__ __launch_bounds__(512, 8) void fused_kernel(
    const uint4* __restrict__ xp,
    const unsigned short* __restrict__ wa2f,
    const unsigned short* __restrict__ wb2f,
    const float* __restrict__ b_off, const float* __restrict__ b_mod,
    float* __restrict__ out)
{
    // pool: [0,14688) patchL (stage..barrier A) | [0,16384) red2 bufs 0-3
    // red1: ph1 partials (dies at barrier B)   | red2 bufs 4-7 (after B)
    __shared__ __align__(16) unsigned char pool[16384];
    __shared__ __align__(16) float red1[8][8][64];    // 16 KB
    __shared__ float lraw[16 * 28];                   // 1.8 KB offsets/mods

    uint4* patchL = (uint4*)pool;
    float* red2lo = (float*)pool;                     // buffers 0-3
    float* red2hi = &red1[0][0][0];                   // buffers 4-7

    int tid = threadIdx.x;
    int l = tid & 63;
    int wid = __builtin_amdgcn_readfirstlane(tid >> 6);  // 0..7
    int m = l & 15, g = l >> 4;
    int strip = (blockIdx.x & 7) * BPX3 + (blockIdx.x >> 3);  // XCD-contiguous
    int b = strip / (HW / 16);              // wave-uniform
    int hw0 = (strip - b * (HW / 16)) * 16;
    int hw = hw0 + m;
    int x = hw % WW, y = hw / WW;
    int y0b = hw0 / WW, x0b = hw0 - y0b * WW;   // strip base (x0b mult of 16)

    const uint4* xpb = xp + (size_t)b * NPL * HWP;

    // ---- Stage 918 items: plane-major, contiguous 288-B runs ----
#pragma unroll
    for (int i = 0; i < 2; ++i) {
        int item = i * 512 + tid;
        if (item < NIT) {
            int pl  = item / 54;
            int rm  = item - pl * 54;
            int run = rm / 18;
            int r18 = rm - run * 18;
            int yy = y0b + run - 1;
            int xx = x0b - 1 + r18;
            bool ok = ((unsigned)yy < HH) && ((unsigned)xx < WW);
            int pos = ok ? (yy * WW + xx) : HW;     // HW = zero slot
            patchL[item] = xpb[(size_t)pl * HWP + pos];
        }
    }
    __syncthreads();                        // barrier S

    // ---- Phase 1: conv partials, 45 units over 8 waves (6/6/6/6/6/5/5/5) ----
    v4f acc0 = {0.f, 0.f, 0.f, 0.f};
    v4f acc1 = {0.f, 0.f, 0.f, 0.f};
    {
        int nu = (wid < 5) ? 6 : 5;         // wave-uniform unit count
#pragma unroll
        for (int i = 0; i < 6; ++i) {
            if (i < nu) {
                int u = wid + 8 * i;        // unit = t*5+ks, uniform
                int t = u / 5, ks = u - 5 * t;
                int r = (t / 3) * 18 + (t % 3) + m;
                v8s a;
                if (ks == 4) {              // flow plane; zero for g>0
                    uint4 t4 = patchL[16 * 54 + r];  // broadcast across g
                    if (g) t4 = (uint4){0u, 0u, 0u, 0u};
                    a = __builtin_bit_cast(v8s, t4);
                } else {
                    int pl = (ks == 0) ? g : (ks == 1) ? 4 + g
                           : (ks == 2) ? 8 + 2 * g : 9 + 2 * g;
                    a = *(const v8s*)&patchL[pl * 54 + r];
                }
                const unsigned short* wp =
                    wa2f + ((size_t)(u * 2)) * 512 + l * 8;
                v8s b0 = *(const v8s*)(wp);
                v8s b1 = *(const v8s*)(wp + 512);
                acc0 = __builtin_amdgcn_mfma_f32_16x16x32_bf16(a, b0, acc0, 0, 0, 0);
                acc1 = __builtin_amdgcn_mfma_f32_16x16x32_bf16(a, b1, acc1, 0, 0, 0);
            }
        }
    }

    {                                       // publish 8 dwords/lane (scalar)
#pragma unroll
        for (int j = 0; j < 4; ++j) red1[wid][j][l] = acc0[j];
#pragma unroll
        for (int j = 0; j < 4; ++j) red1[wid][4 + j][l] = acc1[j];
    }
    __syncthreads();                        // barrier A (patchL dead)

    {   // reduce + epilogue: wave w owns output-dword slot j = w
        int j = wid;
        float v = 0.f;
#pragma unroll
        for (int sw = 0; sw < 8; ++sw) v += red1[sw][j][l];
        int r = j & 3;
        int oc = (j < 4) ? m : 16 + m;
        int pos = g * 4 + r;
        if (oc < 18) {
            lraw[pos * 28 + oc] = v + b_off[oc];
        } else if (oc < 27) {
            lraw[pos * 28 + oc] =
                2.0f / (1.0f + __expf(-(v + b_mod[oc - 18])));
        }
    }
    __syncthreads();                        // barrier B (red1 dead)

    // ---- Phase 2: wave w owns tap w; tap 8 split by ks to waves 6/7 ----
    v4f acc[4];
#pragma unroll
    for (int nt = 0; nt < 4; ++nt) acc[nt] = (v4f){0.f, 0.f, 0.f, 0.f};

    auto do_tap = [&](int k) {
        int ky = k / 3, kx = k - 3 * ky;
        float dy = lraw[m * 28 + 2 * k];
        float dx = lraw[m * 28 + 2 * k + 1];
        float mm = lraw[m * 28 + 18 + k];

        float py = (float)(y - 1 + ky) + dy;
        float px = (float)(x - 1 + kx) + dx;
        float fy = floorf(py), fx = floorf(px);
        int   y0 = (int)fy,    x0 = (int)fx;
        float wy = py - fy,    wx = px - fx;
        int   y1 = y0 + 1,     x1 = x0 + 1;

        bool y0v = (y0 >= 0) && (y0 < HH);
        bool y1v = (y1 >= 0) && (y1 < HH);
        bool x0v = (x0 >= 0) && (x0 < WW);
        bool x1v = (x1 >= 0) && (x1 < WW);

        float w00 = (1.f - wy) * (1.f - wx) * ((y0v && x0v) ? mm : 0.f);
        float w01 = (1.f - wy) * wx         * ((y0v && x1v) ? mm : 0.f);
        float w10 = wy * (1.f - wx)         * ((y1v && x0v) ? mm : 0.f);
        float w11 = wy * wx                 * ((y1v && x1v) ? mm : 0.f);

        int y0c = min(max(y0, 0), HH - 1), y1c = min(max(y1, 0), HH - 1);
        int x0c = min(max(x0, 0), WW - 1), x1c = min(max(x1, 0), WW - 1);
        int i00 = y0c * WW + x0c, i01 = y0c * WW + x1c;
        int i10 = y1c * WW + x0c, i11 = y1c * WW + x1c;

        const uint4* p0 = xpb + (size_t)(8 + 2 * g) * HWP;
        const uint4* p1 = p0 + HWP;

        uint4 a00 = p0[i00];
        uint4 a01 = p0[i01];
        uint4 a10 = p0[i10];
        uint4 a11 = p0[i11];
        uint4 c00 = p1[i00];
        uint4 c01 = p1[i01];
        uint4 c10 = p1[i10];
        uint4 c11 = p1[i11];

        uint4 ov0, ov1;
        ov0.x = bil2(a00.x, a01.x, a10.x, a11.x, w00, w01, w10, w11);
        ov0.y = bil2(a00.y, a01.y, a10.y, a11.y, w00, w01, w10, w11);
        ov0.z = bil2(a00.z, a01.z, a10.z, a11.z, w00, w01, w10, w11);
        ov0.w = bil2(a00.w, a01.w, a10.w, a11.w, w00, w01, w10, w11);
        ov1.x = bil2(c00.x, c01.x, c10.x, c11.x, w00, w01, w10, w11);
        ov1.y = bil2(c00.y, c01.y, c10.y, c11.y, w00, w01, w10, w11);
        ov1.z = bil2(c00.z, c01.z, c10.z, c11.z, w00, w01, w10, w11);
        ov1.w = bil2(c00.w, c01.w, c10.w, c11.w, w00, w01, w10, w11);
        v8s af0 = __builtin_bit_cast(v8s, ov0);
        v8s af1 = __builtin_bit_cast(v8s, ov1);

#pragma unroll
        for (int nt = 0; nt < 4; ++nt) {
            const unsigned short* wp0 =
                wb2f + ((size_t)((k * 2 + 0) * 4 + nt)) * 512 + l * 8;
            const unsigned short* wp1 =
                wb2f + ((size_t)((k * 2 + 1) * 4 + nt)) * 512 + l * 8;
            v8s bb0 = *(const v8s*)wp0;
            v8s bb1 = *(const v8s*)wp1;
            acc[nt] = __builtin_amdgcn_mfma_f32_16x16x32_bf16(af0, bb0, acc[nt], 0, 0, 0);
            acc[nt] = __builtin_amdgcn_mfma_f32_16x16x32_bf16(af1, bb1, acc[nt], 0, 0, 0);
        }
    };

    auto do_half = [&](int k, int ks) {
        int ky = k / 3, kx = k - 3 * ky;
        float dy = lraw[m * 28 + 2 * k];
        float dx = lraw[m * 28 + 2 * k + 1];
        float mm = lraw[m * 28 + 18 + k];

        float py = (float)(y - 1 + ky) + dy;
        float px = (float)(x - 1 + kx) + dx;
        float fy = floorf(py), fx = floorf(px);
        int   y0 = (int)fy,    x0 = (int)fx;
        float wy = py - fy,    wx = px - fx;
        int   y1 = y0 + 1,     x1 = x0 + 1;

        bool y0v = (y0 >= 0) && (y0 < HH);
        bool y1v = (y1 >= 0) && (y1 < HH);
        bool x0v = (x0 >= 0) && (x0 < WW);
        bool x1v = (x1 >= 0) && (x1 < WW);

        float w00 = (1.f - wy) * (1.f - wx) * ((y0v && x0v) ? mm : 0.f);
        float w01 = (1.f - wy) * wx         * ((y0v && x1v) ? mm : 0.f);
        float w10 = wy * (1.f - wx)         * ((y1v && x0v) ? mm : 0.f);
        float w11 = wy * wx                 * ((y1v && x1v) ? mm : 0.f);

        int y0c = min(max(y0, 0), HH - 1), y1c = min(max(y1, 0), HH - 1);
        int x0c = min(max(x0, 0), WW - 1), x1c = min(max(x1, 0), WW - 1);
        int i00 = y0c * WW + x0c, i01 = y0c * WW + x1c;
        int i10 = y1c * WW + x0c, i11 = y1c * WW + x1c;

        const uint4* pk = xpb + (size_t)(8 + 2 * g + ks) * HWP;
        uint4 a00 = pk[i00];
        uint4 a01 = pk[i01];
        uint4 a10 = pk[i10];
        uint4 a11 = pk[i11];

        uint4 ov;
        ov.x = bil2(a00.x, a01.x, a10.x, a11.x, w00, w01, w10, w11);
        ov.y = bil2(a00.y, a01.y, a10.y, a11.y, w00, w01, w10, w11);
        ov.z = bil2(a00.z, a01.z, a10.z, a11.z, w00, w01, w10, w11);
        ov.w = bil2(a00.w, a01.w, a10.w, a11.w, w00, w01, w10, w11);
        v8s af = __builtin_bit_cast(v8s, ov);

#pragma unroll
        for (int nt = 0; nt < 4; ++nt) {
            const unsigned short* wp =
                wb2f + ((size_t)((k * 2 + ks) * 4 + nt)) * 512 + l * 8;
            v8s bb = *(const v8s*)wp;
            acc[nt] = __builtin_amdgcn_mfma_f32_16x16x32_bf16(af, bb, acc[nt], 0, 0, 0);
        }
    };

    do_tap(wid);
    if (wid == 6) do_half(8, 0);
    if (wid == 7) do_half(8, 1);

    // ---- Single-stage reduction: 8 buffers across pool(0-3) + red1(4-7) ----
    {
        float* rb = (wid < 4) ? (red2lo + (size_t)wid * 16 * 64)
                              : (red2hi + (size_t)(wid - 4) * 16 * 64);
#pragma unroll
        for (int nt = 0; nt < 4; ++nt)
#pragma unroll
            for (int r = 0; r < 4; ++r)
                rb[(nt * 4 + r) * 64 + l] = acc[nt][r];
    }
    __syncthreads();                        // barrier C (only ph2 barrier)
    {   // wave w reduces slots {nt*4+r0, +1} over all 8 buffers
        int nt = wid >> 1, r0 = (wid & 1) * 2;
        float v0 = 0.f, v1 = 0.f;
#pragma unroll
        for (int bu = 0; bu < 4; ++bu) {
            v0 += red2lo[((size_t)bu * 16 + nt * 4 + r0) * 64 + l];
            v1 += red2lo[((size_t)bu * 16 + nt * 4 + r0 + 1) * 64 + l];
            v0 += red2hi[((size_t)bu * 16 + nt * 4 + r0) * 64 + l];
            v1 += red2hi[((size_t)bu * 16 + nt * 4 + r0 + 1) * 64 + l];
        }
        float* op = out + ((size_t)(b * COUT + nt * 16 + m)) * HW
                  + hw0 + g * 4 + r0;
        float2 s2 = {v0, v1};
        *(float2*)op = s2;
    }
}

extern "C" void kernel_launch(void* const* d_in, const int* in_sizes, int n_in,
                              void* d_out, int out_size, void* d_ws, size_t ws_size,
                              hipStream_t stream)
{
    const float* frame_i = (const float*)d_in[0];
    const float* frame_j = (const float*)d_in[1];
    const float* flow_ij = (const float*)d_in[2];
    const float* w_off   = (const float*)d_in[3];
    const float* b_off   = (const float*)d_in[4];
    const float* w_mod   = (const float*)d_in[5];
    const float* b_mod   = (const float*)d_in[6];
    const float* w_reg   = (const float*)d_in[7];
    float* out = (float*)d_out;

    // workspace: xp uint4[BB*NPL*HWP] (~10 MB) | Wa2f | Wb2f
    uint4* xp = (uint4*)d_ws;
    unsigned short* wa2f = (unsigned short*)(xp + (size_t)BB * NPL * HWP);
    unsigned short* wb2f = wa2f + NA;

    prep_kernel<<<PXB2 + PWBLK + 1, 256, 0, stream>>>(
        frame_i, frame_j, flow_ij, w_off, w_mod, w_reg, xp, wa2f, wb2f);

    fused_kernel<<<NSTRIP, 512, 0, stream>>>(
        xp, wa2f, wb2f, b_off, b_mod, out);
}